// Round 11
// baseline (1202.779 us; speedup 1.0000x reference)
//
#include <hip/hip_runtime.h>
#include <hip/hip_bf16.h>
#include <cstdint>
#include <cstddef>

#define S_ 256
#define N_ 1024
#define H_ 512
#define AD_ 128
static constexpr int M_TOTAL = N_ * S_;   // 262144 rows per stream (m = s*N + n)

typedef __attribute__((ext_vector_type(8))) short short8;
typedef __attribute__((ext_vector_type(4))) float f32x4;

typedef const __attribute__((address_space(1))) unsigned int* gas_ptr;
typedef __attribute__((address_space(3))) unsigned int* las_ptr;

// pack 8 f32 -> 8 bf16 (RNE)
__device__ __forceinline__ short8 pack8(float4 a, float4 b) {
  union { short8 s; __hip_bfloat162 h[4]; } u;
  u.h[0] = __float22bfloat162_rn(make_float2(a.x, a.y));
  u.h[1] = __float22bfloat162_rn(make_float2(a.z, a.w));
  u.h[2] = __float22bfloat162_rn(make_float2(b.x, b.y));
  u.h[3] = __float22bfloat162_rn(make_float2(b.z, b.w));
  return u.s;
}

// ---------------------------------------------------------------------------
// K0: W1 [H][AD] f32 -> MFMA-fragment-ordered bf16 (B-frag = linear 16B/lane).
// ---------------------------------------------------------------------------
__global__ __launch_bounds__(256) void k_w1frag(
    const float* __restrict__ w1_pre, const float* __restrict__ w1_fol,
    unsigned short* __restrict__ w1f) {
  int idx = blockIdx.x * 256 + threadIdx.x;  // 0..65535
  int st = blockIdx.y;
  const float* w1 = st ? w1_fol : w1_pre;
  int j = idx & 7;
  int lane = (idx >> 3) & 63;
  int c = (idx >> 9) & 7;
  int kk = idx >> 12;
  int k = kk * 32 + ((lane >> 4) << 3) + j;
  int d = c * 16 + (lane & 15);
  __hip_bfloat16 hb = __float2bfloat16(w1[(size_t)k * AD_ + d]);
  w1f[(size_t)st * 65536 + idx] = *(unsigned short*)&hb;
}

// ---------------------------------------------------------------------------
// K1: inclusive prefix sum of is_valid -> pos (rank-1), per stream.
// ---------------------------------------------------------------------------
__global__ __launch_bounds__(1024) void k_scan(
    const int* __restrict__ valid_pre, const int* __restrict__ valid_fol,
    int* __restrict__ pos) {
  const int st = blockIdx.x;
  const int* valid = st ? valid_fol : valid_pre;
  __shared__ int buf[1024];
  const int t = threadIdx.x;
  buf[t] = valid[t];
  __syncthreads();
  for (int off = 1; off < 1024; off <<= 1) {
    int v = (t >= off) ? buf[t - off] : 0;
    __syncthreads();
    buf[t] += v;
    __syncthreads();
  }
  pos[st * N_ + t] = buf[t] - 1;
}

// ---------------------------------------------------------------------------
// K2: logits GEMM, counted-vmcnt schedule. Persistent 256 blocks x 512 thr
// (8 waves). Wave owns 16 rows per group; A via global_load_lds (clean
// 2-rows-x-512B instrs, XOR-swizzled source) into wave-PRIVATE dbuf LDS
// (no barriers ever). Quarters of K (128 floats = 4 chunks): at each
// half-quarter an exact `s_waitcnt vmcnt(24)` keeps {8 gloads + 16 B-loads}
// permanently in flight. ds_reads are inline asm (compiler can't insert
// conservative waits) + lgkmcnt(0) + sched_barrier per guide rule 18.
// B double-banked 2-chunks-deep in regs from L2-resident w1f.
// ---------------------------------------------------------------------------
#define LOAD_B(ARR, CK)                                                     \
  {                                                                         \
    _Pragma("unroll")                                                       \
    for (int cc_ = 0; cc_ < 8; ++cc_)                                       \
      ARR[cc_] = *(const short8*)(bb + ((CK) & 15) * 4096 + cc_ * 512);     \
  }

#define ISSUE_A(GRPN, QN, BUFN)                                             \
  {                                                                         \
    const unsigned char* gb_ = embB +                                       \
        (size_t)((((GRPN) & 15) * 128) + w * 16) * 2048 + (QN) * 512;       \
    _Pragma("unroll")                                                       \
    for (int i_ = 0; i_ < 8; ++i_) {                                        \
      int rl_ = 2 * i_ + g2;                                                \
      const unsigned char* s_ = gb_ + rl_ * 2048 + (lb ^ ((rl_ & 7) << 5)); \
      __builtin_amdgcn_global_load_lds((gas_ptr)s_,                         \
          (las_ptr)(wlds + (BUFN) * 8192 + i_ * 1024), 16, 0, 0);           \
    }                                                                       \
  }

#define WAITV24()                                          \
  asm volatile("s_waitcnt vmcnt(24)" ::: "memory");        \
  __builtin_amdgcn_sched_barrier(0)

#define CPAIR(CL0, QQ, BA, BB_)                                             \
  {                                                                         \
    unsigned o0_ = ldsw + ((QQ) & 1) * 8192 +                               \
                   ((((CL0) * 128) + kq * 32) ^ rsw);                       \
    unsigned o1_ = ldsw + ((QQ) & 1) * 8192 +                               \
                   (((((CL0) + 1) * 128) + kq * 32) ^ rsw);                 \
    float4 x0_, x1_, y0_, y1_;                                              \
    asm volatile("ds_read_b128 %0, %4 offset:0\n\t"                         \
                 "ds_read_b128 %1, %4 offset:16\n\t"                        \
                 "ds_read_b128 %2, %5 offset:0\n\t"                         \
                 "ds_read_b128 %3, %5 offset:16"                            \
                 : "=&v"(x0_), "=&v"(x1_), "=&v"(y0_), "=&v"(y1_)           \
                 : "v"(o0_), "v"(o1_));                                     \
    asm volatile("s_waitcnt lgkmcnt(0)" ::);                                \
    __builtin_amdgcn_sched_barrier(0);                                      \
    short8 a0_ = pack8(x0_, x1_);                                           \
    short8 a1_ = pack8(y0_, y1_);                                           \
    _Pragma("unroll")                                                       \
    for (int cc_ = 0; cc_ < 8; ++cc_) {                                     \
      acc[cc_] = __builtin_amdgcn_mfma_f32_16x16x32_bf16(a0_, BA[cc_],      \
                                                         acc[cc_], 0, 0, 0);\
      acc[cc_] = __builtin_amdgcn_mfma_f32_16x16x32_bf16(a1_, BB_[cc_],     \
                                                         acc[cc_], 0, 0, 0);\
    }                                                                       \
  }

__global__ __launch_bounds__(512) void k_logits(
    const float* __restrict__ emb_pre, const float* __restrict__ emb_fol,
    const unsigned short* __restrict__ w1f,
    const float* __restrict__ w2_pre, const float* __restrict__ w2_fol,
    float* __restrict__ logits) {
  __shared__ __align__(16) unsigned char As[131072];  // 8 waves x 2 buf x 8 KB

  const int gb = blockIdx.x;              // 0..255
  const int st = gb >> 7;
  const int mbase = (gb & 127) * 2048;    // stream-local row base (16 groups)
  const float* __restrict__ emb = st ? emb_fol : emb_pre;
  const float* __restrict__ w2  = st ? w2_fol : w2_pre;
  const unsigned char* embB = (const unsigned char*)(emb + (size_t)mbase * H_);

  const int t = threadIdx.x, w = t >> 6, lane = t & 63;
  const int r16 = lane & 15, kq = lane >> 4;
  const int g2 = lane >> 5;               // row parity within a gload instr
  const int lb = (lane & 31) * 16;        // byte within 512B quarter-row
  const unsigned rsw = (unsigned)((r16 & 7) << 5);
  const unsigned short* __restrict__ bb =
      w1f + (size_t)st * 65536 + (size_t)lane * 8;

  unsigned char* wlds = As + w * 16384;
  const unsigned ldsw =
      (unsigned)(uintptr_t)(__attribute__((address_space(3))) unsigned char*)
          wlds + (unsigned)(r16 * 512);

  float w2v0[8], w2v1[8];
#pragma unroll
  for (int cc = 0; cc < 8; ++cc) {
    w2v0[cc] = w2[(cc * 16 + r16) * 2 + 0];
    w2v1[cc] = w2[(cc * 16 + r16) * 2 + 1];
  }

  short8 B01a[8], B01b[8], B23a[8], B23b[8];

  // prologue: prime A(grp0,Q0)->buf0 and B chunks 0,1
  ISSUE_A(0, 0, 0);
  LOAD_B(B01a, 0);
  LOAD_B(B01b, 1);

  for (int grp = 0; grp < 16; ++grp) {
    f32x4 acc[8];
#pragma unroll
    for (int cc = 0; cc < 8; ++cc) acc[cc] = (f32x4){0.f, 0.f, 0.f, 0.f};

#pragma unroll
    for (int Q = 0; Q < 4; ++Q) {
      // quarter start: issue B bank for chunks 2,3 and A for next quarter
      LOAD_B(B23a, Q * 4 + 2);
      LOAD_B(B23b, Q * 4 + 3);
      ISSUE_A((Q == 3) ? (grp + 1) : grp, (Q + 1) & 3, (Q + 1) & 1);
      WAITV24();                 // A(Q) + B01 landed; B23 + A(next) in flight
      CPAIR(0, Q, B01a, B01b);   // chunks 4Q, 4Q+1
      // mid quarter: issue B bank for next quarter's chunks 0,1
      LOAD_B(B01a, Q * 4 + 4);
      LOAD_B(B01b, Q * 4 + 5);
      WAITV24();                 // B23 landed; A(next) + B01' in flight
      CPAIR(2, Q, B23a, B23b);   // chunks 4Q+2, 4Q+3
    }

    // epilogue: tanh (exp-form), @W2, 16-lane reduce, write logits
#pragma unroll
    for (int q = 0; q < 4; ++q) {
      float p0 = 0.f, p1 = 0.f;
#pragma unroll
      for (int cc = 0; cc < 8; ++cc) {
        float xc = fminf(fmaxf(acc[cc][q], -10.f), 10.f);
        float e  = __expf(2.f * xc);
        float th = (e - 1.f) / (e + 1.f);
        p0 += th * w2v0[cc];
        p1 += th * w2v1[cc];
      }
      p0 += __shfl_xor(p0, 1); p0 += __shfl_xor(p0, 2);
      p0 += __shfl_xor(p0, 4); p0 += __shfl_xor(p0, 8);
      p1 += __shfl_xor(p1, 1); p1 += __shfl_xor(p1, 2);
      p1 += __shfl_xor(p1, 4); p1 += __shfl_xor(p1, 8);
      if (r16 == 0) {
        int m = mbase + grp * 128 + w * 16 + kq * 4 + q;
        *(float2*)&logits[((size_t)st * M_TOTAL + m) * 2] =
            make_float2(p0, p1);
      }
    }
  }
}

// ---------------------------------------------------------------------------
// K3: per (stream, n): double softmax over s (source space), fold r-mean.
// logits layout [st][s][n][2]; wbar [st][n][s].
// ---------------------------------------------------------------------------
template <bool MAXRED>
__device__ __forceinline__ float blockRed(float v, float* buf) {
#pragma unroll
  for (int off = 32; off; off >>= 1) {
    float o = __shfl_xor(v, off);
    v = MAXRED ? fmaxf(v, o) : (v + o);
  }
  __syncthreads();
  if ((threadIdx.x & 63) == 0) buf[threadIdx.x >> 6] = v;
  __syncthreads();
  float r = buf[0];
#pragma unroll
  for (int i = 1; i < 4; ++i) r = MAXRED ? fmaxf(r, buf[i]) : (r + buf[i]);
  return r;
}

__global__ __launch_bounds__(256) void k_softmax(
    const float* __restrict__ logits,
    const unsigned char* __restrict__ mask_pre, const unsigned char* __restrict__ mask_fol,
    float* __restrict__ wbar) {
  const int n  = blockIdx.x;
  const int st = blockIdx.y;
  const unsigned char* mask = st ? mask_fol : mask_pre;
  const int s = threadIdx.x;

  float2 l = *(const float2*)&logits[((size_t)st * M_TOTAL + (size_t)s * N_ + n) * 2];
  const bool mk = mask[(size_t)n * S_ + s] != 0;

  __shared__ float buf[4];
  float q[2];
  float lv[2] = {l.x, l.y};
#pragma unroll
  for (int r = 0; r < 2; ++r) {
    float m1 = blockRed<true>(lv[r], buf);
    float e1 = __expf(lv[r] - m1);
    float s1 = blockRed<false>(e1, buf);
    float p1 = e1 / s1;                       // first softmax (unmasked)
    float v  = mk ? -INFINITY : p1;           // mask the probabilities
    float m2 = blockRed<true>(v, buf);
    float e2 = mk ? 0.f : __expf(v - m2);
    float s2 = blockRed<false>(e2, buf);
    q[r] = e2 / s2;                           // second softmax
  }
  wbar[((size_t)st * N_ + n) * S_ + s] = 0.5f * (q[0] + q[1]);
}

// ---------------------------------------------------------------------------
// K4: PV in memory order. Block = (st, n-chunk of 16, s-half). Per s-step one
// 32 KB contiguous burst (16 adjacent n-rows x full H). part[st][sh][n][h].
// ---------------------------------------------------------------------------
__global__ __launch_bounds__(512) void k_pv2(
    const float* __restrict__ emb_pre, const float* __restrict__ emb_fol,
    const float* __restrict__ wbar,
    float* __restrict__ part) {
  const int bid = blockIdx.x;          // 0..255
  const int st  = bid >> 7;
  const int idx = bid & 127;
  const int nc  = idx >> 1;            // 0..63
  const int sh  = idx & 1;             // 0..1
  const int n0 = nc * 16, s0 = sh * 128;
  const float* __restrict__ emb = st ? emb_fol : emb_pre;

  const int t = threadIdx.x;
  const int nl = t >> 5;               // 0..15 (n-row within chunk)
  const int c0 = (t & 31) * 4;         // h-base; acc j covers c0 + j*128

  __shared__ float wl[16][128];
  for (int i = t; i < 2048; i += 512) {
    int j = i >> 7, sl = i & 127;
    wl[j][sl] = wbar[((size_t)st * N_ + n0 + j) * S_ + s0 + sl];
  }
  __syncthreads();

  float4 acc[4], cur[4], nxt[4];
#pragma unroll
  for (int j = 0; j < 4; ++j) acc[j] = (float4){0.f, 0.f, 0.f, 0.f};

  // s descending (most recently L3-resident rows first)
  const float* rowp = emb + ((size_t)(s0 + 127) * N_ + n0 + nl) * H_ + c0;
  const size_t SSTR = (size_t)N_ * H_;
#pragma unroll
  for (int j = 0; j < 4; ++j) cur[j] = *(const float4*)(rowp + j * 128);

  for (int sl = 127; sl >= 0; --sl) {
    const float* nrow = rowp - SSTR;
    if (sl > 0) {
#pragma unroll
      for (int j = 0; j < 4; ++j) nxt[j] = *(const float4*)(nrow + j * 128);
    }
    const float wv = wl[nl][sl];
#pragma unroll
    for (int j = 0; j < 4; ++j) {
      acc[j].x += wv * cur[j].x;
      acc[j].y += wv * cur[j].y;
      acc[j].z += wv * cur[j].z;
      acc[j].w += wv * cur[j].w;
    }
#pragma unroll
    for (int j = 0; j < 4; ++j) cur[j] = nxt[j];
    rowp = nrow;
  }

  float* pp = part + (((size_t)(st * 2 + sh) * N_) + n0 + nl) * H_ + c0;
#pragma unroll
  for (int j = 0; j < 4; ++j) *(float4*)(pp + j * 128) = acc[j];
}

// ---------------------------------------------------------------------------
// K5: combine s-halves + valid/pos gather -> out[n][st*512 + h].
// ---------------------------------------------------------------------------
__global__ __launch_bounds__(256) void k_combine(
    const float* __restrict__ part, const int* __restrict__ pos,
    const int* __restrict__ valid_pre, const int* __restrict__ valid_fol,
    float* __restrict__ out) {
  const int n = blockIdx.x, t = threadIdx.x;
  const int st = t >> 7;
  const int c = (t & 127) * 4;
  const int* valid = st ? valid_fol : valid_pre;
  float4 r = {0.f, 0.f, 0.f, 0.f};
  if (valid[n] > 0) {
    int np = pos[st * N_ + n]; if (np < 0) np = 0;
    float4 a = *(const float4*)&part[(((size_t)(st * 2 + 0) * N_) + np) * H_ + c];
    float4 b = *(const float4*)&part[(((size_t)(st * 2 + 1) * N_) + np) * H_ + c];
    r.x = a.x + b.x; r.y = a.y + b.y; r.z = a.z + b.z; r.w = a.w + b.w;
  }
  *(float4*)&out[(size_t)n * 1024 + st * 512 + c] = r;
}

// ---------------------------------------------------------------------------
extern "C" void kernel_launch(void* const* d_in, const int* in_sizes, int n_in,
                              void* d_out, int out_size, void* d_ws, size_t ws_size,
                              hipStream_t stream) {
  const float* emb_pre = (const float*)d_in[0];
  const float* emb_fol = (const float*)d_in[1];
  const unsigned char* mask_pre = (const unsigned char*)d_in[2];
  const unsigned char* mask_fol = (const unsigned char*)d_in[3];
  const int* valid_pre = (const int*)d_in[4];
  const int* valid_fol = (const int*)d_in[5];
  const float* w1_pre = (const float*)d_in[6];
  const float* w2_pre = (const float*)d_in[7];
  const float* w1_fol = (const float*)d_in[8];
  const float* w2_fol = (const float*)d_in[9];
  float* out = (float*)d_out;

  char* ws = (char*)d_ws;
  unsigned short* w1f = (unsigned short*)ws;                    // 256 KiB
  int*   pos    = (int*)(ws + 262144);                          // 8 KiB
  float* logits = (float*)(ws + 270336);                        // 4 MiB  [2][S][N][2]
  float* wbar   = (float*)(ws + 270336 + 4194304);              // 2 MiB  [2][N][S]
  float* part   = (float*)(ws + 270336 + 4194304 + 2097152);    // 8 MiB  [2][2][N][H]

  hipLaunchKernelGGL(k_w1frag, dim3(256, 2), dim3(256), 0, stream,
                     w1_pre, w1_fol, w1f);
  hipLaunchKernelGGL(k_scan, dim3(2), dim3(1024), 0, stream,
                     valid_pre, valid_fol, pos);
  hipLaunchKernelGGL(k_logits, dim3(256), dim3(512), 0, stream,
                     emb_pre, emb_fol, w1f, w2_pre, w2_fol, logits);
  hipLaunchKernelGGL(k_softmax, dim3(N_, 2), dim3(256), 0, stream,
                     logits, mask_pre, mask_fol, wbar);
  hipLaunchKernelGGL(k_pv2, dim3(256), dim3(512), 0, stream,
                     emb_pre, emb_fol, wbar, part);
  hipLaunchKernelGGL(k_combine, dim3(N_), dim3(256), 0, stream,
                     part, pos, valid_pre, valid_fol, out);
}

// Round 12
// 473.431 us; speedup vs baseline: 2.5406x; 2.5406x over previous
//
#include <hip/hip_runtime.h>
#include <hip/hip_bf16.h>
#include <cstdint>
#include <cstddef>

#define S_ 256
#define N_ 1024
#define H_ 512
#define AD_ 128
static constexpr int M_TOTAL = N_ * S_;   // 262144 rows per stream (m = s*N + n)

typedef __attribute__((ext_vector_type(8))) short short8;
typedef __attribute__((ext_vector_type(4))) float f32x4;

// pack 8 f32 -> 8 bf16 (RNE)
__device__ __forceinline__ short8 pack8(float4 a, float4 b) {
  union { short8 s; __hip_bfloat162 h[4]; } u;
  u.h[0] = __float22bfloat162_rn(make_float2(a.x, a.y));
  u.h[1] = __float22bfloat162_rn(make_float2(a.z, a.w));
  u.h[2] = __float22bfloat162_rn(make_float2(b.x, b.y));
  u.h[3] = __float22bfloat162_rn(make_float2(b.z, b.w));
  return u.s;
}

// ---------------------------------------------------------------------------
// K0: W1 [H][AD] f32 -> MFMA-fragment-ordered bf16 (B-frag = linear 16B/lane).
// ---------------------------------------------------------------------------
__global__ __launch_bounds__(256) void k_w1frag(
    const float* __restrict__ w1_pre, const float* __restrict__ w1_fol,
    unsigned short* __restrict__ w1f) {
  int idx = blockIdx.x * 256 + threadIdx.x;  // 0..65535
  int st = blockIdx.y;
  const float* w1 = st ? w1_fol : w1_pre;
  int j = idx & 7;
  int lane = (idx >> 3) & 63;
  int c = (idx >> 9) & 7;
  int kk = idx >> 12;
  int k = kk * 32 + ((lane >> 4) << 3) + j;
  int d = c * 16 + (lane & 15);
  __hip_bfloat16 hb = __float2bfloat16(w1[(size_t)k * AD_ + d]);
  w1f[(size_t)st * 65536 + idx] = *(unsigned short*)&hb;
}

// ---------------------------------------------------------------------------
// K1: inclusive prefix sum of is_valid -> pos (rank-1), per stream.
// ---------------------------------------------------------------------------
__global__ __launch_bounds__(1024) void k_scan(
    const int* __restrict__ valid_pre, const int* __restrict__ valid_fol,
    int* __restrict__ pos) {
  const int st = blockIdx.x;
  const int* valid = st ? valid_fol : valid_pre;
  __shared__ int buf[1024];
  const int t = threadIdx.x;
  buf[t] = valid[t];
  __syncthreads();
  for (int off = 1; off < 1024; off <<= 1) {
    int v = (t >= off) ? buf[t - off] : 0;
    __syncthreads();
    buf[t] += v;
    __syncthreads();
  }
  pos[st * N_ + t] = buf[t] - 1;
}

// ---------------------------------------------------------------------------
// logits body (round-8 verified): 512 thr = 8 waves x 32 rows = 256 rows.
// B staged once into LDS (128 KB) -> K-loop vmcnt stream is pure A-loads;
// 3-slot A register pipeline; no K-loop barriers.
// ---------------------------------------------------------------------------
__device__ __forceinline__ void lg_body(
    const float* __restrict__ emb, const unsigned short* __restrict__ w1f_st,
    const float* __restrict__ w2, float* __restrict__ logits_st,
    int m0, unsigned short* Bs, int t) {
  const int w = t >> 6, lane = t & 63;
  const int r16 = lane & 15, kq = lane >> 4;

  // stage B: linear 128 KB copy from L2-resident w1f
  {
    const uint4* src = (const uint4*)w1f_st;
    uint4* dst = (uint4*)Bs;
#pragma unroll
    for (int i = 0; i < 16; ++i) dst[t + i * 512] = src[t + i * 512];
  }
  __syncthreads();

  const unsigned short* bb = Bs + lane * 8;
  const float* a0 = emb + (size_t)(m0 + w * 32 + r16) * H_ + kq * 8;

  f32x4 acc[2][8];
#pragma unroll
  for (int f = 0; f < 2; ++f)
#pragma unroll
    for (int c = 0; c < 8; ++c) acc[f][c] = (f32x4){0.f, 0.f, 0.f, 0.f};

  float4 xb[3][2][2];  // [slot][frag][half] — all static after full unroll
#pragma unroll
  for (int p = 0; p < 3; ++p)
#pragma unroll
    for (int f = 0; f < 2; ++f) {
      const float* ap = a0 + f * (16 * H_) + p * 32;
      xb[p][f][0] = *(const float4*)ap;
      xb[p][f][1] = *(const float4*)(ap + 4);
    }

#pragma unroll
  for (int kk = 0; kk < 16; ++kk) {
    const int sl = kk % 3;
    short8 b[8];
    const unsigned short* bp = bb + kk * 4096;
#pragma unroll
    for (int cc = 0; cc < 8; ++cc) b[cc] = *(const short8*)(bp + cc * 512);
    short8 af0 = pack8(xb[sl][0][0], xb[sl][0][1]);
    short8 af1 = pack8(xb[sl][1][0], xb[sl][1][1]);
    if (kk + 3 < 16) {
#pragma unroll
      for (int f = 0; f < 2; ++f) {
        const float* ap = a0 + f * (16 * H_) + (kk + 3) * 32;
        xb[sl][f][0] = *(const float4*)ap;
        xb[sl][f][1] = *(const float4*)(ap + 4);
      }
    }
#pragma unroll
    for (int cc = 0; cc < 8; ++cc) {
      acc[0][cc] = __builtin_amdgcn_mfma_f32_16x16x32_bf16(af0, b[cc], acc[0][cc], 0, 0, 0);
      acc[1][cc] = __builtin_amdgcn_mfma_f32_16x16x32_bf16(af1, b[cc], acc[1][cc], 0, 0, 0);
    }
  }

  // epilogue: tanh (exp-form), @W2, 16-lane reduce, write logits
  float w2v0[8], w2v1[8];
#pragma unroll
  for (int cc = 0; cc < 8; ++cc) {
    w2v0[cc] = w2[(cc * 16 + r16) * 2 + 0];
    w2v1[cc] = w2[(cc * 16 + r16) * 2 + 1];
  }
#pragma unroll
  for (int f = 0; f < 2; ++f) {
#pragma unroll
    for (int q = 0; q < 4; ++q) {
      float p0 = 0.f, p1 = 0.f;
#pragma unroll
      for (int cc = 0; cc < 8; ++cc) {
        float xc = fminf(fmaxf(acc[f][cc][q], -10.f), 10.f);
        float e  = __expf(2.f * xc);
        float th = (e - 1.f) / (e + 1.f);
        p0 += th * w2v0[cc];
        p1 += th * w2v1[cc];
      }
      p0 += __shfl_xor(p0, 1); p0 += __shfl_xor(p0, 2);
      p0 += __shfl_xor(p0, 4); p0 += __shfl_xor(p0, 8);
      p1 += __shfl_xor(p1, 1); p1 += __shfl_xor(p1, 2);
      p1 += __shfl_xor(p1, 4); p1 += __shfl_xor(p1, 8);
      if (r16 == 0) {
        int m = m0 + w * 32 + f * 16 + kq * 4 + q;
        logits_st[(size_t)m * 2 + 0] = p0;
        logits_st[(size_t)m * 2 + 1] = p1;
      }
    }
  }
}

// ---------------------------------------------------------------------------
// PV body (round-8 verified): block idx in [0,128): (n-chunk of 16, s-half).
// Per s-step one 32 KB contiguous burst. part_st[sh][n][h].
// ---------------------------------------------------------------------------
__device__ __forceinline__ void pv_body(
    const float* __restrict__ emb, const float* __restrict__ wbar_st,
    float* __restrict__ part_st, int idx, float (*wl)[128], int t) {
  const int nc = idx >> 1;             // 0..63
  const int sh = idx & 1;              // 0..1
  const int n0 = nc * 16, s0 = sh * 128;

  const int nl = t >> 5;               // 0..15 (n-row within chunk)
  const int c0 = (t & 31) * 4;         // h-base; acc j covers c0 + j*128

  for (int i = t; i < 2048; i += 512) {
    int j = i >> 7, sl = i & 127;
    wl[j][sl] = wbar_st[(size_t)(n0 + j) * S_ + s0 + sl];
  }
  __syncthreads();

  float4 acc[4], cur[4], nxt[4];
#pragma unroll
  for (int j = 0; j < 4; ++j) acc[j] = (float4){0.f, 0.f, 0.f, 0.f};

  const float* rowp = emb + ((size_t)(s0 + 127) * N_ + n0 + nl) * H_ + c0;
  const size_t SSTR = (size_t)N_ * H_;
#pragma unroll
  for (int j = 0; j < 4; ++j) cur[j] = *(const float4*)(rowp + j * 128);

  for (int sl = 127; sl >= 0; --sl) {
    const float* nrow = rowp - SSTR;
    if (sl > 0) {
#pragma unroll
      for (int j = 0; j < 4; ++j) nxt[j] = *(const float4*)(nrow + j * 128);
    }
    const float wv = wl[nl][sl];
#pragma unroll
    for (int j = 0; j < 4; ++j) {
      acc[j].x += wv * cur[j].x;
      acc[j].y += wv * cur[j].y;
      acc[j].z += wv * cur[j].z;
      acc[j].w += wv * cur[j].w;
    }
#pragma unroll
    for (int j = 0; j < 4; ++j) cur[j] = nxt[j];
    rowp = nrow;
  }

  float* pp = part_st + ((size_t)sh * N_ + n0 + nl) * H_ + c0;
#pragma unroll
  for (int j = 0; j < 4; ++j) *(float4*)(pp + j * 128) = acc[j];
}

// ---------------------------------------------------------------------------
// Stand-alone per-stream kernels
// ---------------------------------------------------------------------------
__global__ __launch_bounds__(512) void k_logits_s(
    const float* __restrict__ emb, const unsigned short* __restrict__ w1f_st,
    const float* __restrict__ w2, float* __restrict__ logits_st) {
  __shared__ __align__(16) unsigned short Bs[65536];   // 128 KB
  lg_body(emb, w1f_st, w2, logits_st, blockIdx.x * 256, Bs, threadIdx.x);
}

__global__ __launch_bounds__(512) void k_pv_s(
    const float* __restrict__ emb, const float* __restrict__ wbar_st,
    float* __restrict__ part_st) {
  __shared__ __align__(16) float wl[16][128];
  pv_body(emb, wbar_st, part_st, blockIdx.x, wl, threadIdx.x);
}

// combined: blocks [0,1024) = logits(stream B); [1024,1152) = PV(stream A)
__global__ __launch_bounds__(512) void k_mix(
    const float* __restrict__ embB, const unsigned short* __restrict__ w1fB,
    const float* __restrict__ w2B, float* __restrict__ logitsB,
    const float* __restrict__ embA, const float* __restrict__ wbarA,
    float* __restrict__ partA) {
  __shared__ __align__(16) unsigned char smem[131072];
  const int bid = blockIdx.x;
  if (bid < 1024) {
    lg_body(embB, w1fB, w2B, logitsB, bid * 256,
            (unsigned short*)smem, threadIdx.x);
  } else {
    pv_body(embA, wbarA, partA, bid - 1024, (float(*)[128])smem, threadIdx.x);
  }
}

// ---------------------------------------------------------------------------
// K3: per n: double softmax over s (source space), fold r-mean (per stream).
// logits layout [s][n][2] (stream-resolved); wbar [n][s].
// ---------------------------------------------------------------------------
template <bool MAXRED>
__device__ __forceinline__ float blockRed(float v, float* buf) {
#pragma unroll
  for (int off = 32; off; off >>= 1) {
    float o = __shfl_xor(v, off);
    v = MAXRED ? fmaxf(v, o) : (v + o);
  }
  __syncthreads();
  if ((threadIdx.x & 63) == 0) buf[threadIdx.x >> 6] = v;
  __syncthreads();
  float r = buf[0];
#pragma unroll
  for (int i = 1; i < 4; ++i) r = MAXRED ? fmaxf(r, buf[i]) : (r + buf[i]);
  return r;
}

__global__ __launch_bounds__(256) void k_softmax_s(
    const float* __restrict__ logits_st,
    const unsigned char* __restrict__ mask_st,
    float* __restrict__ wbar_st) {
  const int n = blockIdx.x;
  const int s = threadIdx.x;

  float2 l = *(const float2*)&logits_st[((size_t)s * N_ + n) * 2];
  const bool mk = mask_st[(size_t)n * S_ + s] != 0;

  __shared__ float buf[4];
  float q[2];
  float lv[2] = {l.x, l.y};
#pragma unroll
  for (int r = 0; r < 2; ++r) {
    float m1 = blockRed<true>(lv[r], buf);
    float e1 = __expf(lv[r] - m1);
    float s1 = blockRed<false>(e1, buf);
    float p1 = e1 / s1;                       // first softmax (unmasked)
    float v  = mk ? -INFINITY : p1;           // mask the probabilities
    float m2 = blockRed<true>(v, buf);
    float e2 = mk ? 0.f : __expf(v - m2);
    float s2 = blockRed<false>(e2, buf);
    q[r] = e2 / s2;                           // second softmax
  }
  wbar_st[(size_t)n * S_ + s] = 0.5f * (q[0] + q[1]);
}

// ---------------------------------------------------------------------------
// K5: combine s-halves + valid/pos gather -> out[n][st*512 + h].
// ---------------------------------------------------------------------------
__global__ __launch_bounds__(256) void k_combine(
    const float* __restrict__ part, const int* __restrict__ pos,
    const int* __restrict__ valid_pre, const int* __restrict__ valid_fol,
    float* __restrict__ out) {
  const int n = blockIdx.x, t = threadIdx.x;
  const int st = t >> 7;
  const int c = (t & 127) * 4;
  const int* valid = st ? valid_fol : valid_pre;
  float4 r = {0.f, 0.f, 0.f, 0.f};
  if (valid[n] > 0) {
    int np = pos[st * N_ + n]; if (np < 0) np = 0;
    float4 a = *(const float4*)&part[(((size_t)(st * 2 + 0) * N_) + np) * H_ + c];
    float4 b = *(const float4*)&part[(((size_t)(st * 2 + 1) * N_) + np) * H_ + c];
    r.x = a.x + b.x; r.y = a.y + b.y; r.z = a.z + b.z; r.w = a.w + b.w;
  }
  *(float4*)&out[(size_t)n * 1024 + st * 512 + c] = r;
}

// ---------------------------------------------------------------------------
extern "C" void kernel_launch(void* const* d_in, const int* in_sizes, int n_in,
                              void* d_out, int out_size, void* d_ws, size_t ws_size,
                              hipStream_t stream) {
  const float* emb_pre = (const float*)d_in[0];
  const float* emb_fol = (const float*)d_in[1];
  const unsigned char* mask_pre = (const unsigned char*)d_in[2];
  const unsigned char* mask_fol = (const unsigned char*)d_in[3];
  const int* valid_pre = (const int*)d_in[4];
  const int* valid_fol = (const int*)d_in[5];
  const float* w1_pre = (const float*)d_in[6];
  const float* w2_pre = (const float*)d_in[7];
  const float* w1_fol = (const float*)d_in[8];
  const float* w2_fol = (const float*)d_in[9];
  float* out = (float*)d_out;

  char* ws = (char*)d_ws;
  unsigned short* w1f = (unsigned short*)ws;                    // 256 KiB
  int*   pos    = (int*)(ws + 262144);                          // 8 KiB
  float* logits = (float*)(ws + 270336);                        // 4 MiB  [2][S][N][2]
  float* wbar   = (float*)(ws + 270336 + 4194304);              // 2 MiB  [2][N][S]
  float* part   = (float*)(ws + 270336 + 4194304 + 2097152);    // 8 MiB  [2][2][N][H]

  const unsigned short* w1f_pre = w1f;
  const unsigned short* w1f_fol = w1f + 65536;
  float* logits_pre = logits;
  float* logits_fol = logits + (size_t)M_TOTAL * 2;
  float* wbar_pre = wbar;
  float* wbar_fol = wbar + (size_t)N_ * S_;
  float* part_pre = part;
  float* part_fol = part + (size_t)2 * N_ * H_;

  hipLaunchKernelGGL(k_w1frag, dim3(256, 2), dim3(256), 0, stream,
                     w1_pre, w1_fol, w1f);
  hipLaunchKernelGGL(k_scan, dim3(2), dim3(1024), 0, stream,
                     valid_pre, valid_fol, pos);
  // stage 1: logits(pre)
  hipLaunchKernelGGL(k_logits_s, dim3(1024), dim3(512), 0, stream,
                     emb_pre, w1f_pre, w2_pre, logits_pre);
  // stage 2: softmax(pre)
  hipLaunchKernelGGL(k_softmax_s, dim3(N_), dim3(256), 0, stream,
                     logits_pre, mask_pre, wbar_pre);
  // stage 3: logits(fol)  ||  PV(pre)   — one dispatch, co-resident blocks
  hipLaunchKernelGGL(k_mix, dim3(1152), dim3(512), 0, stream,
                     emb_fol, w1f_fol, w2_fol, logits_fol,
                     emb_pre, wbar_pre, part_pre);
  // stage 4: softmax(fol)
  hipLaunchKernelGGL(k_softmax_s, dim3(N_), dim3(256), 0, stream,
                     logits_fol, mask_fol, wbar_fol);
  // stage 5: PV(fol)
  hipLaunchKernelGGL(k_pv_s, dim3(128), dim3(512), 0, stream,
                     emb_fol, wbar_fol, part_fol);
  // stage 6: combine + gather
  hipLaunchKernelGGL(k_combine, dim3(N_), dim3(256), 0, stream,
                     part, pos, valid_pre, valid_fol, out);
}

// Round 13
// 473.097 us; speedup vs baseline: 2.5424x; 1.0007x over previous
//
#include <hip/hip_runtime.h>
#include <hip/hip_bf16.h>
#include <cstdint>
#include <cstddef>

#define S_ 256
#define N_ 1024
#define H_ 512
#define AD_ 128
static constexpr int M_TOTAL = N_ * S_;   // 262144 rows per stream (m = s*N + n)

typedef __attribute__((ext_vector_type(8))) short short8;
typedef __attribute__((ext_vector_type(4))) float f32x4;

// ---------------------------------------------------------------------------
// K0: W1 [H][AD] f32 -> MFMA-fragment-ordered bf16 (B-frag = linear 16B/lane).
// ---------------------------------------------------------------------------
__global__ __launch_bounds__(256) void k_w1frag(
    const float* __restrict__ w1_pre, const float* __restrict__ w1_fol,
    unsigned short* __restrict__ w1f) {
  int idx = blockIdx.x * 256 + threadIdx.x;  // 0..65535
  int st = blockIdx.y;
  const float* w1 = st ? w1_fol : w1_pre;
  int j = idx & 7;
  int lane = (idx >> 3) & 63;
  int c = (idx >> 9) & 7;
  int kk = idx >> 12;
  int k = kk * 32 + ((lane >> 4) << 3) + j;
  int d = c * 16 + (lane & 15);
  __hip_bfloat16 hb = __float2bfloat16(w1[(size_t)k * AD_ + d]);
  w1f[(size_t)st * 65536 + idx] = *(unsigned short*)&hb;
}

// ---------------------------------------------------------------------------
// K1: inclusive prefix sum of is_valid -> pos (rank-1), per stream.
// ---------------------------------------------------------------------------
__global__ __launch_bounds__(1024) void k_scan(
    const int* __restrict__ valid_pre, const int* __restrict__ valid_fol,
    int* __restrict__ pos) {
  const int st = blockIdx.x;
  const int* valid = st ? valid_fol : valid_pre;
  __shared__ int buf[1024];
  const int t = threadIdx.x;
  buf[t] = valid[t];
  __syncthreads();
  for (int off = 1; off < 1024; off <<= 1) {
    int v = (t >= off) ? buf[t - off] : 0;
    __syncthreads();
    buf[t] += v;
    __syncthreads();
  }
  pos[st * N_ + t] = buf[t] - 1;
}

// ---------------------------------------------------------------------------
// K2: logits GEMM, WAVE-SPECIALIZED. 1024 thr = 16 waves:
//   waves 0-7  (consumers): 16 rows each; per chunk 1 swizzled ds_read_b128
//     (A frag bf16) + 8 B ds_reads + 8 MFMA. B staged once to LDS (128 KB).
//   waves 8-15 (producers): ONLY stream A: per chunk 2x1KB global loads,
//     f32->bf16 cvt in reg, swizzled ds_write_b64 into 3-slot ring (8KB/slot),
//     loads issued 2 chunks ahead. Producers issue ~pure loads -> full rate.
// M-tile 128 rows; 16 chunks of K=32. One barrier per chunk.
// ---------------------------------------------------------------------------
__global__ __launch_bounds__(1024) void k_logits(
    const float* __restrict__ emb_pre, const float* __restrict__ emb_fol,
    const unsigned short* __restrict__ w1f,
    const float* __restrict__ w2_pre, const float* __restrict__ w2_fol,
    float* __restrict__ logits) {
  __shared__ __align__(16) unsigned short Bs[65536];     // 128 KB W1 frags
  __shared__ __align__(16) unsigned char Abuf[24576];    // 3 slots x 8 KB

  const int bid = blockIdx.x;
  const int st = bid >> 11;                  // 2048 blocks per stream
  const int m0 = (bid & 2047) * 128;
  const float* __restrict__ emb = st ? emb_fol : emb_pre;
  const float* __restrict__ w2  = st ? w2_fol : w2_pre;

  const int t = threadIdx.x;
  const int w = t >> 6, lane = t & 63;
  const int r16 = lane & 15, kq = lane >> 4;

  // stage B cooperatively (L2-resident, linear)
  {
    const uint4* src = (const uint4*)(w1f + (size_t)st * 65536);
    uint4* dst = (uint4*)Bs;
#pragma unroll
    for (int i = 0; i < 8; ++i) dst[t + i * 1024] = src[t + i * 1024];
  }

  if (w >= 8) {
    // ================= PRODUCER =================
    const int pw = w - 8;                    // 0..7
    const int rl = pw * 16 + (lane >> 3);    // lane's row for instr j adds j*8
    const int colg = lane & 7;               // 16B granule within 128B chunk-row
    // per chunk kk, instr j (rows +j*8): src float offset
    const float* base0 = emb + (size_t)(m0 + rl) * H_ + colg * 4;
    const float* base1 = emb + (size_t)(m0 + rl + 8) * H_ + colg * 4;

    // LDS write addr pieces (row includes +j*8)
    const int row0 = rl, row1 = rl + 8;
    const int G = colg >> 1, half = colg & 1;
    const unsigned wa0 = (unsigned)(row0 * 64 + ((G ^ ((row0 >> 1) & 3)) * 16) + half * 8);
    const unsigned wa1 = (unsigned)(row1 * 64 + ((G ^ ((row1 >> 1) & 3)) * 16) + half * 8);

    float4 rA0, rA1, rB0, rB1;
    // prologue: load chunk0 -> rA, chunk1 -> rB, write chunk0 (slot 0)
    rA0 = *(const float4*)(base0 + 0 * 32);
    rA1 = *(const float4*)(base1 + 0 * 32);
    rB0 = *(const float4*)(base0 + 1 * 32);
    rB1 = *(const float4*)(base1 + 1 * 32);
    {
      union { unsigned long long u; __hip_bfloat162 h[2]; } p0, p1;
      p0.h[0] = __float22bfloat162_rn(make_float2(rA0.x, rA0.y));
      p0.h[1] = __float22bfloat162_rn(make_float2(rA0.z, rA0.w));
      p1.h[0] = __float22bfloat162_rn(make_float2(rA1.x, rA1.y));
      p1.h[1] = __float22bfloat162_rn(make_float2(rA1.z, rA1.w));
      *(unsigned long long*)&Abuf[0 * 8192 + wa0] = p0.u;
      *(unsigned long long*)&Abuf[0 * 8192 + wa1] = p1.u;
    }
    __syncthreads();

#pragma unroll
    for (int c = 0; c < 16; ++c) {
      if (c < 14) {  // load chunk c+2 into the bank just freed
        if ((c & 1) == 0) {
          rA0 = *(const float4*)(base0 + (c + 2) * 32);
          rA1 = *(const float4*)(base1 + (c + 2) * 32);
        } else {
          rB0 = *(const float4*)(base0 + (c + 2) * 32);
          rB1 = *(const float4*)(base1 + (c + 2) * 32);
        }
      }
      if (c < 15) {  // write chunk c+1 from the other bank
        const unsigned sb = (unsigned)(((c + 1) % 3) * 8192);
        float4 v0 = ((c & 1) == 0) ? rB0 : rA0;
        float4 v1 = ((c & 1) == 0) ? rB1 : rA1;
        union { unsigned long long u; __hip_bfloat162 h[2]; } p0, p1;
        p0.h[0] = __float22bfloat162_rn(make_float2(v0.x, v0.y));
        p0.h[1] = __float22bfloat162_rn(make_float2(v0.z, v0.w));
        p1.h[0] = __float22bfloat162_rn(make_float2(v1.x, v1.y));
        p1.h[1] = __float22bfloat162_rn(make_float2(v1.z, v1.w));
        *(unsigned long long*)&Abuf[sb + wa0] = p0.u;
        *(unsigned long long*)&Abuf[sb + wa1] = p1.u;
      }
      __syncthreads();
    }
    // producers done (no epilogue)
  } else {
    // ================= CONSUMER =================
    const int row = w * 16 + r16;
    const unsigned ra = (unsigned)(row * 64 + (kq ^ ((row >> 1) & 3)) * 16);

    f32x4 acc[8];
#pragma unroll
    for (int cc = 0; cc < 8; ++cc) acc[cc] = (f32x4){0.f, 0.f, 0.f, 0.f};

    __syncthreads();   // matches producer prologue barrier

#pragma unroll
    for (int c = 0; c < 16; ++c) {
      short8 a = *(const short8*)&Abuf[(c % 3) * 8192 + ra];
#pragma unroll
      for (int cc = 0; cc < 8; ++cc) {
        short8 b = *(const short8*)&Bs[c * 4096 + cc * 512 + lane * 8];
        acc[cc] = __builtin_amdgcn_mfma_f32_16x16x32_bf16(a, b, acc[cc], 0, 0, 0);
      }
      __syncthreads();
    }

    // epilogue: tanh (exp-form), @W2, 16-lane reduce, write logits
    float w2v0[8], w2v1[8];
#pragma unroll
    for (int cc = 0; cc < 8; ++cc) {
      w2v0[cc] = w2[(cc * 16 + r16) * 2 + 0];
      w2v1[cc] = w2[(cc * 16 + r16) * 2 + 1];
    }
#pragma unroll
    for (int q = 0; q < 4; ++q) {
      float p0 = 0.f, p1 = 0.f;
#pragma unroll
      for (int cc = 0; cc < 8; ++cc) {
        float xc = fminf(fmaxf(acc[cc][q], -10.f), 10.f);
        float e  = __expf(2.f * xc);
        float th = (e - 1.f) / (e + 1.f);
        p0 += th * w2v0[cc];
        p1 += th * w2v1[cc];
      }
      p0 += __shfl_xor(p0, 1); p0 += __shfl_xor(p0, 2);
      p0 += __shfl_xor(p0, 4); p0 += __shfl_xor(p0, 8);
      p1 += __shfl_xor(p1, 1); p1 += __shfl_xor(p1, 2);
      p1 += __shfl_xor(p1, 4); p1 += __shfl_xor(p1, 8);
      if (r16 == 0) {
        int m = m0 + w * 16 + kq * 4 + q;
        logits[((size_t)st * M_TOTAL + m) * 2 + 0] = p0;
        logits[((size_t)st * M_TOTAL + m) * 2 + 1] = p1;
      }
    }
  }
}

// ---------------------------------------------------------------------------
// K3: per (stream, n): double softmax over s (source space), fold r-mean.
// logits layout [st][s][n][2]; wbar [st][n][s].
// ---------------------------------------------------------------------------
template <bool MAXRED>
__device__ __forceinline__ float blockRed(float v, float* buf) {
#pragma unroll
  for (int off = 32; off; off >>= 1) {
    float o = __shfl_xor(v, off);
    v = MAXRED ? fmaxf(v, o) : (v + o);
  }
  __syncthreads();
  if ((threadIdx.x & 63) == 0) buf[threadIdx.x >> 6] = v;
  __syncthreads();
  float r = buf[0];
#pragma unroll
  for (int i = 1; i < 4; ++i) r = MAXRED ? fmaxf(r, buf[i]) : (r + buf[i]);
  return r;
}

__global__ __launch_bounds__(256) void k_softmax(
    const float* __restrict__ logits,
    const unsigned char* __restrict__ mask_pre, const unsigned char* __restrict__ mask_fol,
    float* __restrict__ wbar) {
  const int n  = blockIdx.x;
  const int st = blockIdx.y;
  const unsigned char* mask = st ? mask_fol : mask_pre;
  const int s = threadIdx.x;

  float2 l = *(const float2*)&logits[((size_t)st * M_TOTAL + (size_t)s * N_ + n) * 2];
  const bool mk = mask[(size_t)n * S_ + s] != 0;

  __shared__ float buf[4];
  float q[2];
  float lv[2] = {l.x, l.y};
#pragma unroll
  for (int r = 0; r < 2; ++r) {
    float m1 = blockRed<true>(lv[r], buf);
    float e1 = __expf(lv[r] - m1);
    float s1 = blockRed<false>(e1, buf);
    float p1 = e1 / s1;                       // first softmax (unmasked)
    float v  = mk ? -INFINITY : p1;           // mask the probabilities
    float m2 = blockRed<true>(v, buf);
    float e2 = mk ? 0.f : __expf(v - m2);
    float s2 = blockRed<false>(e2, buf);
    q[r] = e2 / s2;                           // second softmax
  }
  wbar[((size_t)st * N_ + n) * S_ + s] = 0.5f * (q[0] + q[1]);
}

// ---------------------------------------------------------------------------
// K4: PV in memory order. Block = (st, n-chunk of 16, s-half). Per s-step one
// 32 KB contiguous burst (16 adjacent n-rows x full H). part[st][sh][n][h].
// ---------------------------------------------------------------------------
__global__ __launch_bounds__(512) void k_pv2(
    const float* __restrict__ emb_pre, const float* __restrict__ emb_fol,
    const float* __restrict__ wbar,
    float* __restrict__ part) {
  const int bid = blockIdx.x;          // 0..255
  const int st  = bid >> 7;
  const int idx = bid & 127;
  const int nc  = idx >> 1;            // 0..63
  const int sh  = idx & 1;             // 0..1
  const int n0 = nc * 16, s0 = sh * 128;
  const float* __restrict__ emb = st ? emb_fol : emb_pre;

  const int t = threadIdx.x;
  const int nl = t >> 5;               // 0..15 (n-row within chunk)
  const int c0 = (t & 31) * 4;         // h-base; acc j covers c0 + j*128

  __shared__ float wl[16][128];
  for (int i = t; i < 2048; i += 512) {
    int j = i >> 7, sl = i & 127;
    wl[j][sl] = wbar[((size_t)st * N_ + n0 + j) * S_ + s0 + sl];
  }
  __syncthreads();

  float4 acc[4], cur[4], nxt[4];
#pragma unroll
  for (int j = 0; j < 4; ++j) acc[j] = (float4){0.f, 0.f, 0.f, 0.f};

  // s descending (most recently L3-resident rows first)
  const float* rowp = emb + ((size_t)(s0 + 127) * N_ + n0 + nl) * H_ + c0;
  const size_t SSTR = (size_t)N_ * H_;
#pragma unroll
  for (int j = 0; j < 4; ++j) cur[j] = *(const float4*)(rowp + j * 128);

  for (int sl = 127; sl >= 0; --sl) {
    const float* nrow = rowp - SSTR;
    if (sl > 0) {
#pragma unroll
      for (int j = 0; j < 4; ++j) nxt[j] = *(const float4*)(nrow + j * 128);
    }
    const float wv = wl[nl][sl];
#pragma unroll
    for (int j = 0; j < 4; ++j) {
      acc[j].x += wv * cur[j].x;
      acc[j].y += wv * cur[j].y;
      acc[j].z += wv * cur[j].z;
      acc[j].w += wv * cur[j].w;
    }
#pragma unroll
    for (int j = 0; j < 4; ++j) cur[j] = nxt[j];
    rowp = nrow;
  }

  float* pp = part + (((size_t)(st * 2 + sh) * N_) + n0 + nl) * H_ + c0;
#pragma unroll
  for (int j = 0; j < 4; ++j) *(float4*)(pp + j * 128) = acc[j];
}

// ---------------------------------------------------------------------------
// K5: combine s-halves + valid/pos gather -> out[n][st*512 + h].
// ---------------------------------------------------------------------------
__global__ __launch_bounds__(256) void k_combine(
    const float* __restrict__ part, const int* __restrict__ pos,
    const int* __restrict__ valid_pre, const int* __restrict__ valid_fol,
    float* __restrict__ out) {
  const int n = blockIdx.x, t = threadIdx.x;
  const int st = t >> 7;
  const int c = (t & 127) * 4;
  const int* valid = st ? valid_fol : valid_pre;
  float4 r = {0.f, 0.f, 0.f, 0.f};
  if (valid[n] > 0) {
    int np = pos[st * N_ + n]; if (np < 0) np = 0;
    float4 a = *(const float4*)&part[(((size_t)(st * 2 + 0) * N_) + np) * H_ + c];
    float4 b = *(const float4*)&part[(((size_t)(st * 2 + 1) * N_) + np) * H_ + c];
    r.x = a.x + b.x; r.y = a.y + b.y; r.z = a.z + b.z; r.w = a.w + b.w;
  }
  *(float4*)&out[(size_t)n * 1024 + st * 512 + c] = r;
}

// ---------------------------------------------------------------------------
extern "C" void kernel_launch(void* const* d_in, const int* in_sizes, int n_in,
                              void* d_out, int out_size, void* d_ws, size_t ws_size,
                              hipStream_t stream) {
  const float* emb_pre = (const float*)d_in[0];
  const float* emb_fol = (const float*)d_in[1];
  const unsigned char* mask_pre = (const unsigned char*)d_in[2];
  const unsigned char* mask_fol = (const unsigned char*)d_in[3];
  const int* valid_pre = (const int*)d_in[4];
  const int* valid_fol = (const int*)d_in[5];
  const float* w1_pre = (const float*)d_in[6];
  const float* w2_pre = (const float*)d_in[7];
  const float* w1_fol = (const float*)d_in[8];
  const float* w2_fol = (const float*)d_in[9];
  float* out = (float*)d_out;

  char* ws = (char*)d_ws;
  unsigned short* w1f = (unsigned short*)ws;                    // 256 KiB
  int*   pos    = (int*)(ws + 262144);                          // 8 KiB
  float* logits = (float*)(ws + 270336);                        // 4 MiB  [2][S][N][2]
  float* wbar   = (float*)(ws + 270336 + 4194304);              // 2 MiB  [2][N][S]
  float* part   = (float*)(ws + 270336 + 4194304 + 2097152);    // 8 MiB  [2][2][N][H]

  hipLaunchKernelGGL(k_w1frag, dim3(256, 2), dim3(256), 0, stream,
                     w1_pre, w1_fol, w1f);
  hipLaunchKernelGGL(k_scan, dim3(2), dim3(1024), 0, stream,
                     valid_pre, valid_fol, pos);
  hipLaunchKernelGGL(k_logits, dim3(4096), dim3(1024), 0, stream,
                     emb_pre, emb_fol, w1f, w2_pre, w2_fol, logits);
  hipLaunchKernelGGL(k_softmax, dim3(N_, 2), dim3(256), 0, stream,
                     logits, mask_pre, mask_fol, wbar);
  hipLaunchKernelGGL(k_pv2, dim3(256), dim3(512), 0, stream,
                     emb_pre, emb_fol, wbar, part);
  hipLaunchKernelGGL(k_combine, dim3(N_), dim3(256), 0, stream,
                     part, pos, valid_pre, valid_fol, out);
}

// Round 14
// 438.619 us; speedup vs baseline: 2.7422x; 1.0786x over previous
//
#include <hip/hip_runtime.h>
#include <hip/hip_bf16.h>
#include <cstdint>
#include <cstddef>

#define S_ 256
#define N_ 1024
#define H_ 512
#define AD_ 128
static constexpr int M_TOTAL = N_ * S_;   // 262144 rows per stream (m = s*N + n)

typedef __attribute__((ext_vector_type(8))) short short8;
typedef __attribute__((ext_vector_type(4))) float f32x4;

// ---------------------------------------------------------------------------
// K0: W1 [H][AD] f32 -> MFMA-fragment-ordered bf16 (B-frag = linear 16B/lane).
// ---------------------------------------------------------------------------
__global__ __launch_bounds__(256) void k_w1frag(
    const float* __restrict__ w1_pre, const float* __restrict__ w1_fol,
    unsigned short* __restrict__ w1f) {
  int idx = blockIdx.x * 256 + threadIdx.x;  // 0..65535
  int st = blockIdx.y;
  const float* w1 = st ? w1_fol : w1_pre;
  int j = idx & 7;
  int lane = (idx >> 3) & 63;
  int c = (idx >> 9) & 7;
  int kk = idx >> 12;
  int k = kk * 32 + ((lane >> 4) << 3) + j;
  int d = c * 16 + (lane & 15);
  __hip_bfloat16 hb = __float2bfloat16(w1[(size_t)k * AD_ + d]);
  w1f[(size_t)st * 65536 + idx] = *(unsigned short*)&hb;
}

// ---------------------------------------------------------------------------
// K1: inclusive prefix sum of is_valid -> pos (rank-1), per stream.
// ---------------------------------------------------------------------------
__global__ __launch_bounds__(1024) void k_scan(
    const int* __restrict__ valid_pre, const int* __restrict__ valid_fol,
    int* __restrict__ pos) {
  const int st = blockIdx.x;
  const int* valid = st ? valid_fol : valid_pre;
  __shared__ int buf[1024];
  const int t = threadIdx.x;
  buf[t] = valid[t];
  __syncthreads();
  for (int off = 1; off < 1024; off <<= 1) {
    int v = (t >= off) ? buf[t - off] : 0;
    __syncthreads();
    buf[t] += v;
    __syncthreads();
  }
  pos[st * N_ + t] = buf[t] - 1;
}

// ---------------------------------------------------------------------------
// K2: logits GEMM, PV2-SHAPED STREAMING. Block = (st, 16-n chunk, s-half);
// 512 thr = 8 waves; 128 s-steps. Per step: block reads 16 n-rows x 2KB =
// one dense 32KB region in pv2's access pattern (per-thread nxt[4] float4
// one step ahead -> loads stay in flight across barriers), cvt -> 16KB
// XOR-swizzled LDS, then each wave does its 16-col tile: 16 chained MFMA
// with B FULLY REGISTER-RESIDENT (loaded once per block), tanh/@W2/shfl
// epilogue, cross-wave reduce, write logits[st][s][n][2]. 2 barriers/step.
// ---------------------------------------------------------------------------
__global__ __launch_bounds__(512) void k_logits(
    const float* __restrict__ emb_pre, const float* __restrict__ emb_fol,
    const unsigned short* __restrict__ w1f,
    const float* __restrict__ w2_pre, const float* __restrict__ w2_fol,
    float* __restrict__ logits) {
  __shared__ __align__(16) unsigned char As[16384];   // 16 rows x 1KB bf16
  __shared__ float part[8][16][2];

  const int bid = blockIdx.x;          // 0..255
  const int st  = bid >> 7;
  const int idx = bid & 127;
  const int nc  = idx >> 1;            // 0..63
  const int sh  = idx & 1;             // 0..1
  const int n0 = nc * 16, s0 = sh * 128;
  const float* __restrict__ emb = st ? emb_fol : emb_pre;
  const float* __restrict__ w2  = st ? w2_fol : w2_pre;

  const int t = threadIdx.x;
  const int w = t >> 6, lane = t & 63;
  const int r16 = lane & 15, kq = lane >> 4;

  // B: wave w's 16-col tile, all 16 K-chunks, register-resident (64 VGPR)
  short8 B[16];
  {
    const unsigned short* bb = w1f + (size_t)st * 65536 + w * 512 + (size_t)lane * 8;
#pragma unroll
    for (int kk = 0; kk < 16; ++kk) B[kk] = *(const short8*)(bb + kk * 4096);
  }
  const float w2v0 = w2[(w * 16 + r16) * 2 + 0];
  const float w2v1 = w2[(w * 16 + r16) * 2 + 1];

  // staging geometry: thread (srow, sl): floats k = sl*4 + j*128 of row srow
  const int srow = t >> 5;             // 0..15
  const int sl   = t & 31;
  const size_t SSTR = (size_t)N_ * H_;
  const float* sbase = emb + ((size_t)s0 * N_ + n0 + srow) * H_ + sl * 4;
  // swizzled LDS write addrs (granule g = j*16 + sl/2, half = sl&1)
  unsigned wadr[4];
#pragma unroll
  for (int j = 0; j < 4; ++j) {
    int g = j * 16 + (sl >> 1);
    wadr[j] = (unsigned)(srow * 1024 + ((g ^ (srow & 7)) * 16) + (sl & 1) * 8);
  }
  // fragment read addrs (granule kk*4+kq of row r16), hoisted
  unsigned radr[16];
#pragma unroll
  for (int kk = 0; kk < 16; ++kk)
    radr[kk] = (unsigned)(r16 * 1024 + (((kk * 4 + kq) ^ (r16 & 7)) * 16));

  float4 nxt[4];
#pragma unroll
  for (int j = 0; j < 4; ++j) nxt[j] = *(const float4*)(sbase + j * 128);
  // prologue: write step 0 into LDS
#pragma unroll
  for (int j = 0; j < 4; ++j) {
    union { unsigned long long u; __hip_bfloat162 h[2]; } p;
    p.h[0] = __float22bfloat162_rn(make_float2(nxt[j].x, nxt[j].y));
    p.h[1] = __float22bfloat162_rn(make_float2(nxt[j].z, nxt[j].w));
    *(unsigned long long*)&As[wadr[j]] = p.u;
  }
  __syncthreads();

  for (int ss = 0; ss < 128; ++ss) {
    // issue next step's HBM loads first (consumed after barrier1 -> ~full
    // step of latency slack; registers, so they fly across barriers)
    if (ss < 127) {
      const float* nb = sbase + (size_t)(ss + 1) * SSTR;
#pragma unroll
      for (int j = 0; j < 4; ++j) nxt[j] = *(const float4*)(nb + j * 128);
    }

    // compute: 16 chained MFMAs, A from LDS, B from regs
    f32x4 acc = (f32x4){0.f, 0.f, 0.f, 0.f};
#pragma unroll
    for (int kk = 0; kk < 16; ++kk) {
      short8 a = *(const short8*)&As[radr[kk]];
      acc = __builtin_amdgcn_mfma_f32_16x16x32_bf16(a, B[kk], acc, 0, 0, 0);
    }

    // epilogue: tanh (exp-form), @W2, reduce over the wave's 16 cols
#pragma unroll
    for (int q = 0; q < 4; ++q) {
      float xc = fminf(fmaxf(acc[q], -10.f), 10.f);
      float e  = __expf(2.f * xc);
      float th = (e - 1.f) / (e + 1.f);
      float p0 = th * w2v0;
      float p1 = th * w2v1;
      p0 += __shfl_xor(p0, 1); p0 += __shfl_xor(p0, 2);
      p0 += __shfl_xor(p0, 4); p0 += __shfl_xor(p0, 8);
      p1 += __shfl_xor(p1, 1); p1 += __shfl_xor(p1, 2);
      p1 += __shfl_xor(p1, 4); p1 += __shfl_xor(p1, 8);
      if (r16 == 0) {
        part[w][kq * 4 + q][0] = p0;
        part[w][kq * 4 + q][1] = p1;
      }
    }
    __syncthreads();  // [1] part ready; As fully consumed

    if (t < 32) {     // cross-wave reduce + write logits (16 rows x 2)
      int row = t >> 1, rr = t & 1;
      float v = 0.f;
#pragma unroll
      for (int g = 0; g < 8; ++g) v += part[g][row][rr];
      logits[((size_t)st * M_TOTAL + (size_t)(s0 + ss) * N_ + n0 + row) * 2 + rr] = v;
    }
    if (ss < 127) {   // cvt + write next step's A into LDS
#pragma unroll
      for (int j = 0; j < 4; ++j) {
        union { unsigned long long u; __hip_bfloat162 h[2]; } p;
        p.h[0] = __float22bfloat162_rn(make_float2(nxt[j].x, nxt[j].y));
        p.h[1] = __float22bfloat162_rn(make_float2(nxt[j].z, nxt[j].w));
        *(unsigned long long*)&As[wadr[j]] = p.u;
      }
    }
    __syncthreads();  // [2] As ready; part safe to overwrite
  }
}

// ---------------------------------------------------------------------------
// K3: per (stream, n): double softmax over s (source space), fold r-mean.
// logits layout [st][s][n][2]; wbar [st][n][s].
// ---------------------------------------------------------------------------
template <bool MAXRED>
__device__ __forceinline__ float blockRed(float v, float* buf) {
#pragma unroll
  for (int off = 32; off; off >>= 1) {
    float o = __shfl_xor(v, off);
    v = MAXRED ? fmaxf(v, o) : (v + o);
  }
  __syncthreads();
  if ((threadIdx.x & 63) == 0) buf[threadIdx.x >> 6] = v;
  __syncthreads();
  float r = buf[0];
#pragma unroll
  for (int i = 1; i < 4; ++i) r = MAXRED ? fmaxf(r, buf[i]) : (r + buf[i]);
  return r;
}

__global__ __launch_bounds__(256) void k_softmax(
    const float* __restrict__ logits,
    const unsigned char* __restrict__ mask_pre, const unsigned char* __restrict__ mask_fol,
    float* __restrict__ wbar) {
  const int n  = blockIdx.x;
  const int st = blockIdx.y;
  const unsigned char* mask = st ? mask_fol : mask_pre;
  const int s = threadIdx.x;

  float2 l = *(const float2*)&logits[((size_t)st * M_TOTAL + (size_t)s * N_ + n) * 2];
  const bool mk = mask[(size_t)n * S_ + s] != 0;

  __shared__ float buf[4];
  float q[2];
  float lv[2] = {l.x, l.y};
#pragma unroll
  for (int r = 0; r < 2; ++r) {
    float m1 = blockRed<true>(lv[r], buf);
    float e1 = __expf(lv[r] - m1);
    float s1 = blockRed<false>(e1, buf);
    float p1 = e1 / s1;                       // first softmax (unmasked)
    float v  = mk ? -INFINITY : p1;           // mask the probabilities
    float m2 = blockRed<true>(v, buf);
    float e2 = mk ? 0.f : __expf(v - m2);
    float s2 = blockRed<false>(e2, buf);
    q[r] = e2 / s2;                           // second softmax
  }
  wbar[((size_t)st * N_ + n) * S_ + s] = 0.5f * (q[0] + q[1]);
}

// ---------------------------------------------------------------------------
// K4: PV in memory order. Block = (st, n-chunk of 16, s-half). Per s-step one
// 32 KB contiguous burst (16 adjacent n-rows x full H). part[st][sh][n][h].
// ---------------------------------------------------------------------------
__global__ __launch_bounds__(512) void k_pv2(
    const float* __restrict__ emb_pre, const float* __restrict__ emb_fol,
    const float* __restrict__ wbar,
    float* __restrict__ part) {
  const int bid = blockIdx.x;          // 0..255
  const int st  = bid >> 7;
  const int idx = bid & 127;
  const int nc  = idx >> 1;            // 0..63
  const int sh  = idx & 1;             // 0..1
  const int n0 = nc * 16, s0 = sh * 128;
  const float* __restrict__ emb = st ? emb_fol : emb_pre;

  const int t = threadIdx.x;
  const int nl = t >> 5;               // 0..15 (n-row within chunk)
  const int c0 = (t & 31) * 4;         // h-base; acc j covers c0 + j*128

  __shared__ float wl[16][128];
  for (int i = t; i < 2048; i += 512) {
    int j = i >> 7, sl = i & 127;
    wl[j][sl] = wbar[((size_t)st * N_ + n0 + j) * S_ + s0 + sl];
  }
  __syncthreads();

  float4 acc[4], cur[4], nxt[4];
#pragma unroll
  for (int j = 0; j < 4; ++j) acc[j] = (float4){0.f, 0.f, 0.f, 0.f};

  // s descending (most recently L3-resident rows first)
  const float* rowp = emb + ((size_t)(s0 + 127) * N_ + n0 + nl) * H_ + c0;
  const size_t SSTR = (size_t)N_ * H_;
#pragma unroll
  for (int j = 0; j < 4; ++j) cur[j] = *(const float4*)(rowp + j * 128);

  for (int sl = 127; sl >= 0; --sl) {
    const float* nrow = rowp - SSTR;
    if (sl > 0) {
#pragma unroll
      for (int j = 0; j < 4; ++j) nxt[j] = *(const float4*)(nrow + j * 128);
    }
    const float wv = wl[nl][sl];
#pragma unroll
    for (int j = 0; j < 4; ++j) {
      acc[j].x += wv * cur[j].x;
      acc[j].y += wv * cur[j].y;
      acc[j].z += wv * cur[j].z;
      acc[j].w += wv * cur[j].w;
    }
#pragma unroll
    for (int j = 0; j < 4; ++j) cur[j] = nxt[j];
    rowp = nrow;
  }

  float* pp = part + (((size_t)(st * 2 + sh) * N_) + n0 + nl) * H_ + c0;
#pragma unroll
  for (int j = 0; j < 4; ++j) *(float4*)(pp + j * 128) = acc[j];
}

// ---------------------------------------------------------------------------
// K5: combine s-halves + valid/pos gather -> out[n][st*512 + h].
// ---------------------------------------------------------------------------
__global__ __launch_bounds__(256) void k_combine(
    const float* __restrict__ part, const int* __restrict__ pos,
    const int* __restrict__ valid_pre, const int* __restrict__ valid_fol,
    float* __restrict__ out) {
  const int n = blockIdx.x, t = threadIdx.x;
  const int st = t >> 7;
  const int c = (t & 127) * 4;
  const int* valid = st ? valid_fol : valid_pre;
  float4 r = {0.f, 0.f, 0.f, 0.f};
  if (valid[n] > 0) {
    int np = pos[st * N_ + n]; if (np < 0) np = 0;
    float4 a = *(const float4*)&part[(((size_t)(st * 2 + 0) * N_) + np) * H_ + c];
    float4 b = *(const float4*)&part[(((size_t)(st * 2 + 1) * N_) + np) * H_ + c];
    r.x = a.x + b.x; r.y = a.y + b.y; r.z = a.z + b.z; r.w = a.w + b.w;
  }
  *(float4*)&out[(size_t)n * 1024 + st * 512 + c] = r;
}

// ---------------------------------------------------------------------------
extern "C" void kernel_launch(void* const* d_in, const int* in_sizes, int n_in,
                              void* d_out, int out_size, void* d_ws, size_t ws_size,
                              hipStream_t stream) {
  const float* emb_pre = (const float*)d_in[0];
  const float* emb_fol = (const float*)d_in[1];
  const unsigned char* mask_pre = (const unsigned char*)d_in[2];
  const unsigned char* mask_fol = (const unsigned char*)d_in[3];
  const int* valid_pre = (const int*)d_in[4];
  const int* valid_fol = (const int*)d_in[5];
  const float* w1_pre = (const float*)d_in[6];
  const float* w2_pre = (const float*)d_in[7];
  const float* w1_fol = (const float*)d_in[8];
  const float* w2_fol = (const float*)d_in[9];
  float* out = (float*)d_out;

  char* ws = (char*)d_ws;
  unsigned short* w1f = (unsigned short*)ws;                    // 256 KiB
  int*   pos    = (int*)(ws + 262144);                          // 8 KiB
  float* logits = (float*)(ws + 270336);                        // 4 MiB  [2][S][N][2]
  float* wbar   = (float*)(ws + 270336 + 4194304);              // 2 MiB  [2][N][S]
  float* part   = (float*)(ws + 270336 + 4194304 + 2097152);    // 8 MiB  [2][2][N][H]

  hipLaunchKernelGGL(k_w1frag, dim3(256, 2), dim3(256), 0, stream,
                     w1_pre, w1_fol, w1f);
  hipLaunchKernelGGL(k_scan, dim3(2), dim3(1024), 0, stream,
                     valid_pre, valid_fol, pos);
  hipLaunchKernelGGL(k_logits, dim3(256), dim3(512), 0, stream,
                     emb_pre, emb_fol, w1f, w2_pre, w2_fol, logits);
  hipLaunchKernelGGL(k_softmax, dim3(N_, 2), dim3(256), 0, stream,
                     logits, mask_pre, mask_fol, wbar);
  hipLaunchKernelGGL(k_pv2, dim3(256), dim3(512), 0, stream,
                     emb_pre, emb_fol, wbar, part);
  hipLaunchKernelGGL(k_combine, dim3(N_), dim3(256), 0, stream,
                     part, pos, valid_pre, valid_fol, out);
}